// Round 19
// baseline (183.560 us; speedup 1.0000x reference)
//
#include <hip/hip_runtime.h>
#include <hip/hip_bf16.h>

#define T_TOK 2048
#define HDIM  2048
#define FDIM  1024
#define NEXP  8
#define KSEL  2
#define NENT  (T_TOK*KSEL)   // 4096 routing entries
#define WMAX1 24             // max 256-row work items
#define PREPB 8192           // streaming blocks in k_prep (block PREPB = routing)

typedef __attribute__((ext_vector_type(8))) short   short8v;
typedef __attribute__((ext_vector_type(4))) float   floatx4;
typedef __attribute__((ext_vector_type(4))) unsigned short ushort4v;

__device__ __forceinline__ unsigned short f2bf(float f) {
  unsigned int u = __builtin_bit_cast(unsigned int, f);
  u += 0x7FFFu + ((u >> 16) & 1u);
  return (unsigned short)(u >> 16);
}

__device__ __forceinline__ short8v cvt8(floatx4 v0, floatx4 v1, float sc) {
  short8v r = { (short)f2bf(v0.x*sc), (short)f2bf(v0.y*sc),
                (short)f2bf(v0.z*sc), (short)f2bf(v0.w*sc),
                (short)f2bf(v1.x*sc), (short)f2bf(v1.y*sc),
                (short)f2bf(v1.z*sc), (short)f2bf(v1.w*sc) };
  return r;
}

__device__ __forceinline__ void gll16(const void* g, void* l) {
  __builtin_amdgcn_global_load_lds(
      (const __attribute__((address_space(1))) unsigned int*)g,
      (__attribute__((address_space(3))) unsigned int*)l, 16, 0, 0);
}

// ---- workspace layout ----
// wsI[0:8) cnt | wsI[16:24) offsets | wsI[24] nWork128 | wsI[25] nWork256
// wsI[48:88) wl128 | wsI[96:120) wl256
// wsI[128:+4096) entry token | (float*)[4096] entry weight | [4096] inv map
// byte 65536: hb (8Mi) | wgb (64Mi) | wdb (32Mi) | act (8Mi) | oe (32Mi)
#define ETOK_OFF 128

// fallback-path zero (never hipMemsetAsync: rocclr fill kernel is slow)
__global__ __launch_bounds__(256) void k_zero(float* __restrict__ p) {
  const int N = T_TOK * HDIM / 4;
  for (int c = blockIdx.x * 256 + threadIdx.x; c < N; c += 2048 * 256) {
    floatx4 z = {0.f, 0.f, 0.f, 0.f};
    *(floatx4*)(p + (size_t)c * 4) = z;
  }
}

// standalone routing (fallback path)
__global__ void k_route(const int* __restrict__ ids, const float* __restrict__ tw,
                        int* __restrict__ wsI) {
  __shared__ int cnt[8], off[8], cur[8];
  const int tid = threadIdx.x;
  if (tid < 8) { cnt[tid] = 0; cur[tid] = 0; }
  __syncthreads();
  for (int g = tid; g < NENT; g += 256)
    atomicAdd(&cnt[ids[g] & 7], 1);
  __syncthreads();
  if (tid == 0) {
    int s = 0, n1 = 0, n2 = 0;
    int* wl1 = wsI + 48;
    int* wl2 = wsI + 96;
    for (int e = 0; e < 8; e++) {
      off[e] = s; wsI[16 + e] = s; wsI[e] = cnt[e];
      int c = cnt[e]; s += c;
      int nb1 = (c + 127) >> 7;
      for (int rb = 0; rb < nb1; rb++) wl1[n1++] = (e << 8) | rb;
      int nb2 = (c + 255) >> 8;
      for (int rb = 0; rb < nb2; rb++) wl2[n2++] = (e << 8) | rb;
    }
    wsI[24] = n1; wsI[25] = n2;
  }
  __syncthreads();
  int*   etok = wsI + ETOK_OFF;
  float* ew   = (float*)(wsI + ETOK_OFF + NENT);
  int*   inv  = wsI + ETOK_OFF + 2 * NENT;
  for (int g = tid; g < NENT; g += 256) {
    int e = ids[g] & 7;
    int pos = atomicAdd(&cur[e], 1);
    int idx = off[e] + pos;
    etok[idx] = g >> 1;
    ew[idx]   = tw[g];
    inv[g]    = idx;
  }
}

// ---- fused prep: hidden->bf16, BOTH weight dequants, AND routing ----
__global__ __launch_bounds__(256) void k_prep(const float* __restrict__ h,
                                              unsigned short* __restrict__ hb,
                                              const float* __restrict__ w,
                                              const float* __restrict__ s,
                                              unsigned short* __restrict__ wgb,
                                              const float* __restrict__ wdn,
                                              const float* __restrict__ sdn,
                                              unsigned short* __restrict__ wdb,
                                              const int* __restrict__ ids,
                                              const float* __restrict__ tw,
                                              int* __restrict__ wsI) {
  if (blockIdx.x == PREPB) {
    __shared__ int cnt[8], off[8], cur[8];
    const int tid = threadIdx.x;
    if (tid < 8) { cnt[tid] = 0; cur[tid] = 0; }
    __syncthreads();
    for (int g = tid; g < NENT; g += 256)
      atomicAdd(&cnt[ids[g] & 7], 1);
    __syncthreads();
    if (tid == 0) {
      int sum = 0, n1 = 0, n2 = 0;
      int* wl1 = wsI + 48;
      int* wl2 = wsI + 96;
      for (int e = 0; e < 8; e++) {
        off[e] = sum; wsI[16 + e] = sum; wsI[e] = cnt[e];
        int c = cnt[e]; sum += c;
        int nb1 = (c + 127) >> 7;
        for (int rb = 0; rb < nb1; rb++) wl1[n1++] = (e << 8) | rb;
        int nb2 = (c + 255) >> 8;
        for (int rb = 0; rb < nb2; rb++) wl2[n2++] = (e << 8) | rb;
      }
      wsI[24] = n1; wsI[25] = n2;
    }
    __syncthreads();
    int*   etok = wsI + ETOK_OFF;
    float* ew   = (float*)(wsI + ETOK_OFF + NENT);
    int*   inv  = wsI + ETOK_OFF + 2 * NENT;
    for (int g = threadIdx.x; g < NENT; g += 256) {
      int e = ids[g] & 7;
      int pos = atomicAdd(&cur[e], 1);
      int idx = off[e] + pos;
      etok[idx] = g >> 1;
      ew[idx]   = tw[g];
      inv[g]    = idx;
    }
    return;
  }

  const int gid = blockIdx.x * 256 + threadIdx.x;
  const int NH = T_TOK * HDIM / 8;                  // 524288
  if (gid < NH) {
    const floatx4 v0 = *(const floatx4*)(h + (size_t)gid * 8);
    const floatx4 v1 = *(const floatx4*)(h + (size_t)gid * 8 + 4);
    *(short8v*)(hb + (size_t)gid * 8) = cvt8(v0, v1, 1.f);
  }
  const int NG = NEXP * 2 * FDIM * HDIM / 8;        // 4194304
  for (int c = gid; c < NG; c += PREPB * 256) {
    int h8  = c & 255;
    int row = c >> 8;
    int e   = row >> 11;
    int orow = row & 2047;
    float sc = s[e * 256 + (orow >> 7) * 16 + (h8 >> 4)];
    const floatx4 v0 = *(const floatx4*)(w + (size_t)c * 8);
    const floatx4 v1 = *(const floatx4*)(w + (size_t)c * 8 + 4);
    *(short8v*)(wgb + (size_t)c * 8) = cvt8(v0, v1, sc);
  }
  const int ND = NEXP * HDIM * FDIM / 8;            // 2097152
  for (int c = gid; c < ND; c += PREPB * 256) {
    int f8  = c & 127;
    int row = c >> 7;
    int e   = row >> 11;
    int hh  = row & 2047;
    float sc = sdn[e * 128 + (hh >> 7) * 8 + (f8 >> 4)];
    const floatx4 v0 = *(const floatx4*)(wdn + (size_t)c * 8);
    const floatx4 v1 = *(const floatx4*)(wdn + (size_t)c * 8 + 4);
    *(short8v*)(wdb + (size_t)c * 8) = cvt8(v0, v1, sc);
  }
}

// ---- GEMM1: act = silu(h@Wg^T)*(h@Wu^T); BM=256 x 32 act-cols, BK=128 ----
// grid (WMAX1, 32): wave w owns rows [w*64,w*64+64). 16 K-iterations.
__global__ __launch_bounds__(256, 2) void k_gemm1n(
    const unsigned short* __restrict__ hb,
    const unsigned short* __restrict__ wgb,
    const int* __restrict__ wsI,
    unsigned short* __restrict__ act)
{
  if ((int)blockIdx.x >= wsI[25]) return;
  const int item = wsI[96 + blockIdx.x];
  const int e    = item >> 8;
  const int r0   = (item & 255) << 8;
  const int cnt  = wsI[e];
  const int off  = wsI[16 + e];
  const int c0   = blockIdx.y * 32;          // act col base
  const int* etok = wsI + ETOK_OFF;

  __shared__ unsigned short As[256][128];    // 64 KB
  __shared__ unsigned short Bs[64][128];     // 16 KB

  const int tid = threadIdx.x, lane = tid & 63, w = tid >> 6;
  const int kg = lane >> 4, l15 = lane & 15;
  const int lr4 = lane >> 4, lc16 = lane & 15;   // gll16: 4 rows x 16 chunks

  // A: wave w stages its own 64 rows; 16 gll16 per iter (4 rows each)
  unsigned int aoff[16];
#pragma unroll
  for (int i = 0; i < 16; i++) {
    int ra  = w * 64 + i * 4 + lr4;
    int swz = (lc16 ^ (ra & 15)) * 8;
    int ent = r0 + ra; if (ent >= cnt) ent = cnt - 1;
    aoff[i] = (unsigned)etok[off + ent] * 2048u + (unsigned)swz;
  }
  // B: 64 rows total; wave stages 16 rows via 4 gll16
  unsigned int boff[4];
#pragma unroll
  for (int i = 0; i < 4; i++) {
    int rb  = w * 16 + i * 4 + lr4;          // [0,64): 32 gate + 32 up
    int swz = (lc16 ^ (rb & 15)) * 8;
    int gr  = (rb < 32) ? (c0 + rb) : (1024 + c0 + rb - 32);
    boff[i] = ((unsigned)e * 2048u + (unsigned)gr) * 2048u + (unsigned)swz;
  }

  floatx4 acc[4][4] = {};

  for (int k0 = 0; k0 < HDIM; k0 += 128) {
#pragma unroll
    for (int i = 0; i < 16; i++)
      gll16(hb + aoff[i] + k0, (char*)As + (w * 16 + i) * 1024);
#pragma unroll
    for (int i = 0; i < 4; i++)
      gll16(wgb + boff[i] + k0, (char*)Bs + (w * 4 + i) * 1024);
    __syncthreads();

    const char* Ab = (const char*)As;
    const char* Bb = (const char*)Bs;
#pragma unroll
    for (int ks = 0; ks < 4; ks++) {
      short8v a[4], b[4];
#pragma unroll
      for (int m = 0; m < 4; m++) {
        int r = w * 64 + m * 16 + l15;
        a[m] = *(const short8v*)(Ab + r * 256 + (((ks * 4 + kg) ^ (r & 15)) << 4));
      }
#pragma unroll
      for (int n = 0; n < 4; n++) {
        int rb = n * 16 + l15;
        b[n] = *(const short8v*)(Bb + rb * 256 + (((ks * 4 + kg) ^ (rb & 15)) << 4));
      }
#pragma unroll
      for (int m = 0; m < 4; m++)
#pragma unroll
        for (int n = 0; n < 4; n++)
          acc[m][n] = __builtin_amdgcn_mfma_f32_16x16x32_bf16(a[m], b[n], acc[m][n], 0, 0, 0);
    }
    __syncthreads();
  }

#pragma unroll
  for (int m = 0; m < 4; m++) {
    int rbase = r0 + w * 64 + m * 16 + kg * 4;
#pragma unroll
    for (int reg = 0; reg < 4; reg++) {
      int rr = rbase + reg;
      if (rr < cnt) {
#pragma unroll
        for (int n = 0; n < 2; n++) {
          float g = acc[m][n][reg];       // gate col c0 + n*16 + l15
          float u = acc[m][n + 2][reg];   // matching up
          float a = g / (1.f + __expf(-g)) * u;
          act[(size_t)(off + rr) * FDIM + c0 + n * 16 + l15] = f2bf(a);
        }
      }
    }
  }
}

// ---- GEMM2: oe[entry] = w_entry * (act @ Wdn^T); BM=256 x 64 h-cols, BK=128 ----
// grid (WMAX1, 32): 8 K-iterations.
__global__ __launch_bounds__(256, 2) void k_gemm2n(
    const unsigned short* __restrict__ wdb,
    const int* __restrict__ wsI,
    const unsigned short* __restrict__ act,
    float* __restrict__ oe)
{
  if ((int)blockIdx.x >= wsI[25]) return;
  const int item = wsI[96 + blockIdx.x];
  const int e    = item >> 8;
  const int r0   = (item & 255) << 8;
  const int cnt  = wsI[e];
  const int off  = wsI[16 + e];
  const int c0   = blockIdx.y * 64;          // h col base
  const float* ew = (const float*)(wsI + ETOK_OFF + NENT);

  __shared__ unsigned short As[256][128];    // 64 KB
  __shared__ unsigned short Bs[64][128];     // 16 KB

  const int tid = threadIdx.x, lane = tid & 63, w = tid >> 6;
  const int kg = lane >> 4, l15 = lane & 15;
  const int lr4 = lane >> 4, lc16 = lane & 15;

  unsigned int aoff[16];
#pragma unroll
  for (int i = 0; i < 16; i++) {
    int ra  = w * 64 + i * 4 + lr4;
    int swz = (lc16 ^ (ra & 15)) * 8;
    int ent = r0 + ra; if (ent >= cnt) ent = cnt - 1;
    aoff[i] = (unsigned)(off + ent) * 1024u + (unsigned)swz;
  }
  unsigned int boff[4];
#pragma unroll
  for (int i = 0; i < 4; i++) {
    int rb  = w * 16 + i * 4 + lr4;          // [0,64) h-rows
    int swz = (lc16 ^ (rb & 15)) * 8;
    boff[i] = ((unsigned)e * 2048u + (unsigned)(c0 + rb)) * 1024u + (unsigned)swz;
  }

  floatx4 acc[4][4] = {};

  for (int k0 = 0; k0 < FDIM; k0 += 128) {
#pragma unroll
    for (int i = 0; i < 16; i++)
      gll16(act + aoff[i] + k0, (char*)As + (w * 16 + i) * 1024);
#pragma unroll
    for (int i = 0; i < 4; i++)
      gll16(wdb + boff[i] + k0, (char*)Bs + (w * 4 + i) * 1024);
    __syncthreads();

    const char* Ab = (const char*)As;
    const char* Bb = (const char*)Bs;
#pragma unroll
    for (int ks = 0; ks < 4; ks++) {
      short8v a[4], b[4];
#pragma unroll
      for (int m = 0; m < 4; m++) {
        int r = w * 64 + m * 16 + l15;
        a[m] = *(const short8v*)(Ab + r * 256 + (((ks * 4 + kg) ^ (r & 15)) << 4));
      }
#pragma unroll
      for (int n = 0; n < 4; n++) {
        int rb = n * 16 + l15;
        b[n] = *(const short8v*)(Bb + rb * 256 + (((ks * 4 + kg) ^ (rb & 15)) << 4));
      }
#pragma unroll
      for (int m = 0; m < 4; m++)
#pragma unroll
        for (int n = 0; n < 4; n++)
          acc[m][n] = __builtin_amdgcn_mfma_f32_16x16x32_bf16(a[m], b[n], acc[m][n], 0, 0, 0);
    }
    __syncthreads();
  }

#pragma unroll
  for (int m = 0; m < 4; m++) {
    int rbase = r0 + w * 64 + m * 16 + kg * 4;
#pragma unroll
    for (int reg = 0; reg < 4; reg++) {
      int rr = rbase + reg;
      if (rr < cnt) {
        float wgt = ew[off + rr];
#pragma unroll
        for (int n = 0; n < 4; n++)
          oe[(size_t)(off + rr) * HDIM + c0 + n * 16 + l15] = wgt * acc[m][n][reg];
      }
    }
  }
}

__global__ __launch_bounds__(256) void k_reduce(const int* __restrict__ wsI,
                                                const float* __restrict__ oe,
                                                float* __restrict__ out) {
  int i4 = blockIdx.x * 256 + threadIdx.x;
  if (i4 >= T_TOK * HDIM / 4) return;
  int t  = i4 >> 9;
  int h4 = (i4 & 511) * 4;
  const int* inv = wsI + ETOK_OFF + 2 * NENT;
  int e0 = inv[2 * t], e1 = inv[2 * t + 1];
  floatx4 a = *(const floatx4*)&oe[(size_t)e0 * HDIM + h4];
  floatx4 b = *(const floatx4*)&oe[(size_t)e1 * HDIM + h4];
  floatx4 r = a + b;
  *(floatx4*)&out[(size_t)t * HDIM + h4] = r;
}

// ================= fallback (round-1 passing kernels) =================
__global__ __launch_bounds__(256) void k_gemm1_fb(
    const float* __restrict__ hidden, const float* __restrict__ wgu,
    const float* __restrict__ sgu, const int* __restrict__ wsI,
    unsigned short* __restrict__ act)
{
  const int e = blockIdx.y; const int cnt = wsI[e];
  const int r0 = blockIdx.x * 128; if (r0 >= cnt) return;
  const int off = wsI[16 + e]; const int c0 = blockIdx.z * 64;
  const int* etok = wsI + ETOK_OFF;
  __shared__ unsigned short As[128][40]; __shared__ unsigned short Bs[128][40];
  const int tid = threadIdx.x, lane = tid & 63, wv = tid >> 6;
  const int wr = (wv >> 1) * 64, wc = wv & 1, kg = lane >> 4, l15 = lane & 15;
  floatx4 acc[4][4] = {};
  for (int k0 = 0; k0 < HDIM; k0 += 32) {
#pragma unroll
    for (int c = tid; c < 1024; c += 256) {
      int row = c >> 3, k4 = c & 7;
      int rg = r0 + row; if (rg >= cnt) rg = cnt - 1;
      int tok = etok[off + rg];
      const floatx4 v = *(const floatx4*)&hidden[(size_t)tok * HDIM + k0 + k4 * 4];
      ushort4v o = { f2bf(v.x), f2bf(v.y), f2bf(v.z), f2bf(v.w) };
      *(ushort4v*)&As[row][k4 * 4] = o;
    }
#pragma unroll
    for (int c = tid; c < 1024; c += 256) {
      int row = c >> 3, k4 = c & 7;
      int gr = (row < 64) ? (c0 + row) : (FDIM + c0 + row - 64);
      float s = sgu[e * 256 + (gr >> 7) * 16 + (k0 >> 7)];
      const floatx4 v = *(const floatx4*)&wgu[((size_t)e * 2048 + gr) * HDIM + k0 + k4 * 4];
      ushort4v o = { f2bf(v.x * s), f2bf(v.y * s), f2bf(v.z * s), f2bf(v.w * s) };
      *(ushort4v*)&Bs[row][k4 * 4] = o;
    }
    __syncthreads();
    short8v a[4], b[4];
#pragma unroll
    for (int m = 0; m < 4; m++) a[m] = *(const short8v*)&As[wr + m * 16 + l15][kg * 8];
#pragma unroll
    for (int n = 0; n < 4; n++) {
      int br = (n < 2) ? (wc * 32 + n * 16) : (64 + wc * 32 + (n - 2) * 16);
      b[n] = *(const short8v*)&Bs[br + l15][kg * 8];
    }
#pragma unroll
    for (int m = 0; m < 4; m++)
#pragma unroll
      for (int n = 0; n < 4; n++)
        acc[m][n] = __builtin_amdgcn_mfma_f32_16x16x32_bf16(a[m], b[n], acc[m][n], 0, 0, 0);
    __syncthreads();
  }
#pragma unroll
  for (int m = 0; m < 4; m++) {
    int rbase = r0 + wr + m * 16 + kg * 4;
#pragma unroll
    for (int reg = 0; reg < 4; reg++) {
      int rr = rbase + reg;
      if (rr < cnt) {
#pragma unroll
        for (int n = 0; n < 2; n++) {
          float g = acc[m][n][reg], u = acc[m][n + 2][reg];
          float a = g / (1.f + expf(-g)) * u;
          act[(size_t)(off + rr) * FDIM + c0 + wc * 32 + n * 16 + l15] = f2bf(a);
        }
      }
    }
  }
}

__global__ __launch_bounds__(256) void k_gemm2_fb(
    const float* __restrict__ wdn, const float* __restrict__ sdn,
    const int* __restrict__ wsI, const unsigned short* __restrict__ act,
    float* __restrict__ out)
{
  const int e = blockIdx.y; const int cnt = wsI[e];
  const int r0 = blockIdx.x * 128; if (r0 >= cnt) return;
  const int off = wsI[16 + e]; const int c0 = blockIdx.z * 128;
  const int* etok = wsI + ETOK_OFF;
  const float* ew = (const float*)(wsI + ETOK_OFF + NENT);
  __shared__ unsigned short As[128][40]; __shared__ unsigned short Bs[128][40];
  const int tid = threadIdx.x, lane = tid & 63, wv = tid >> 6;
  const int wr = (wv >> 1) * 64, wc = wv & 1, kg = lane >> 4, l15 = lane & 15;
  floatx4 acc[4][4] = {};
  for (int k0 = 0; k0 < FDIM; k0 += 32) {
#pragma unroll
    for (int c = tid; c < 512; c += 256) {
      int row = c >> 2, k8 = c & 3;
      int rg = r0 + row; if (rg >= cnt) rg = cnt - 1;
      short8v v = *(const short8v*)&act[(size_t)(off + rg) * FDIM + k0 + k8 * 8];
      *(short8v*)&As[row][k8 * 8] = v;
    }
#pragma unroll
    for (int c = tid; c < 1024; c += 256) {
      int row = c >> 3, k4 = c & 7;
      int gr = c0 + row;
      float s = sdn[e * 128 + (gr >> 7) * 8 + (k0 >> 7)];
      const floatx4 v = *(const floatx4*)&wdn[((size_t)e * HDIM + gr) * FDIM + k0 + k4 * 4];
      ushort4v o = { f2bf(v.x * s), f2bf(v.y * s), f2bf(v.z * s), f2bf(v.w * s) };
      *(ushort4v*)&Bs[row][k4 * 4] = o;
    }
    __syncthreads();
    short8v a[4], b[4];
#pragma unroll
    for (int m = 0; m < 4; m++) a[m] = *(const short8v*)&As[wr + m * 16 + l15][kg * 8];
#pragma unroll
    for (int n = 0; n < 4; n++) b[n] = *(const short8v*)&Bs[wc * 64 + n * 16 + l15][kg * 8];
#pragma unroll
    for (int m = 0; m < 4; m++)
#pragma unroll
      for (int n = 0; n < 4; n++)
        acc[m][n] = __builtin_amdgcn_mfma_f32_16x16x32_bf16(a[m], b[n], acc[m][n], 0, 0, 0);
    __syncthreads();
  }
#pragma unroll
  for (int m = 0; m < 4; m++) {
    int rbase = r0 + wr + m * 16 + kg * 4;
#pragma unroll
    for (int reg = 0; reg < 4; reg++) {
      int rr = rbase + reg;
      if (rr < cnt) {
        int tok = etok[off + rr];
        float ww = ew[off + rr];
#pragma unroll
        for (int n = 0; n < 4; n++)
          atomicAdd(&out[(size_t)tok * HDIM + c0 + wc * 64 + n * 16 + l15], ww * acc[m][n][reg]);
      }
    }
  }
}

extern "C" void kernel_launch(void* const* d_in, const int* in_sizes, int n_in,
                              void* d_out, int out_size, void* d_ws, size_t ws_size,
                              hipStream_t stream) {
  const float* hidden = (const float*)d_in[0];
  const float* tw     = (const float*)d_in[1];
  const int*   ids    = (const int*)d_in[2];
  const float* wgu    = (const float*)d_in[3];
  const float* sgu    = (const float*)d_in[4];
  const float* wdn    = (const float*)d_in[5];
  const float* sdn    = (const float*)d_in[6];
  float* out = (float*)d_out;
  int* wsI = (int*)d_ws;

  const size_t NEED = 65536ull + (144ull << 20);
  if (ws_size >= NEED) {
    unsigned short* hb  = (unsigned short*)((char*)d_ws + 65536);
    unsigned short* wgb = hb  + (size_t)T_TOK * HDIM;
    unsigned short* wdb = wgb + (size_t)NEXP * 2 * FDIM * HDIM;
    unsigned short* act = wdb + (size_t)NEXP * HDIM * FDIM;
    float*          oe  = (float*)(act + (size_t)NENT * FDIM);

    k_prep<<<PREPB + 1, 256, 0, stream>>>(hidden, hb, wgu, sgu, wgb,
                                          wdn, sdn, wdb, ids, tw, wsI);

    dim3 g1(WMAX1, 32);
    k_gemm1n<<<g1, 256, 0, stream>>>(hb, wgb, wsI, act);
    dim3 g2(WMAX1, 32);
    k_gemm2n<<<g2, 256, 0, stream>>>(wdb, wsI, act, oe);
    k_reduce<<<T_TOK * HDIM / 4 / 256, 256, 0, stream>>>(wsI, oe, out);
  } else {
    k_zero <<<2048, 256, 0, stream>>>(out);
    k_route<<<1, 256, 0, stream>>>(ids, tw, wsI);
    unsigned short* act = (unsigned short*)((char*)d_ws + 65536);
    dim3 g1(NENT / 128, NEXP, FDIM / 64);
    k_gemm1_fb<<<g1, 256, 0, stream>>>(hidden, wgu, sgu, wsI, act);
    dim3 g2(NENT / 128, NEXP, HDIM / 128);
    k_gemm2_fb<<<g2, 256, 0, stream>>>(wdn, sdn, wsI, act, out);
  }
}

// Round 20
// 177.164 us; speedup vs baseline: 1.0361x; 1.0361x over previous
//
#include <hip/hip_runtime.h>
#include <hip/hip_bf16.h>

#define T_TOK 2048
#define HDIM  2048
#define FDIM  1024
#define NEXP  8
#define KSEL  2
#define NENT  (T_TOK*KSEL)   // 4096 routing entries
#define WMAX1 24             // max 256-row work items
#define PREPB 8192           // streaming blocks in k_prep (block PREPB = routing)

typedef __attribute__((ext_vector_type(8))) short   short8v;
typedef __attribute__((ext_vector_type(4))) float   floatx4;
typedef __attribute__((ext_vector_type(4))) unsigned short ushort4v;

__device__ __forceinline__ unsigned short f2bf(float f) {
  unsigned int u = __builtin_bit_cast(unsigned int, f);
  u += 0x7FFFu + ((u >> 16) & 1u);
  return (unsigned short)(u >> 16);
}

__device__ __forceinline__ short8v cvt8(floatx4 v0, floatx4 v1, float sc) {
  short8v r = { (short)f2bf(v0.x*sc), (short)f2bf(v0.y*sc),
                (short)f2bf(v0.z*sc), (short)f2bf(v0.w*sc),
                (short)f2bf(v1.x*sc), (short)f2bf(v1.y*sc),
                (short)f2bf(v1.z*sc), (short)f2bf(v1.w*sc) };
  return r;
}

__device__ __forceinline__ void gll16(const void* g, void* l) {
  __builtin_amdgcn_global_load_lds(
      (const __attribute__((address_space(1))) unsigned int*)g,
      (__attribute__((address_space(3))) unsigned int*)l, 16, 0, 0);
}

// ---- workspace layout ----
// wsI[0:8) cnt | wsI[16:24) offsets | wsI[24] nWork128 | wsI[25] nWork256
// wsI[48:88) wl128 | wsI[96:120) wl256
// wsI[128:+4096) entry token | (float*)[4096] entry weight | [4096] inv map
// byte 65536: hb (8Mi) | wgb (64Mi) | wdb (32Mi) | act (8Mi)
#define ETOK_OFF 128

// zero d_out (fast, grid-strided; never hipMemsetAsync: rocclr fill is slow)
__global__ __launch_bounds__(256) void k_zero(float* __restrict__ p) {
  const int N = T_TOK * HDIM / 4;
  for (int c = blockIdx.x * 256 + threadIdx.x; c < N; c += 2048 * 256) {
    floatx4 z = {0.f, 0.f, 0.f, 0.f};
    *(floatx4*)(p + (size_t)c * 4) = z;
  }
}

// standalone routing (fallback path)
__global__ void k_route(const int* __restrict__ ids, const float* __restrict__ tw,
                        int* __restrict__ wsI) {
  __shared__ int cnt[8], off[8], cur[8];
  const int tid = threadIdx.x;
  if (tid < 8) { cnt[tid] = 0; cur[tid] = 0; }
  __syncthreads();
  for (int g = tid; g < NENT; g += 256)
    atomicAdd(&cnt[ids[g] & 7], 1);
  __syncthreads();
  if (tid == 0) {
    int s = 0, n1 = 0, n2 = 0;
    int* wl1 = wsI + 48;
    int* wl2 = wsI + 96;
    for (int e = 0; e < 8; e++) {
      off[e] = s; wsI[16 + e] = s; wsI[e] = cnt[e];
      int c = cnt[e]; s += c;
      int nb1 = (c + 127) >> 7;
      for (int rb = 0; rb < nb1; rb++) wl1[n1++] = (e << 8) | rb;
      int nb2 = (c + 255) >> 8;
      for (int rb = 0; rb < nb2; rb++) wl2[n2++] = (e << 8) | rb;
    }
    wsI[24] = n1; wsI[25] = n2;
  }
  __syncthreads();
  int*   etok = wsI + ETOK_OFF;
  float* ew   = (float*)(wsI + ETOK_OFF + NENT);
  int*   inv  = wsI + ETOK_OFF + 2 * NENT;
  for (int g = tid; g < NENT; g += 256) {
    int e = ids[g] & 7;
    int pos = atomicAdd(&cur[e], 1);
    int idx = off[e] + pos;
    etok[idx] = g >> 1;
    ew[idx]   = tw[g];
    inv[g]    = idx;
  }
}

// ---- fused prep: hidden->bf16, BOTH weight dequants, AND routing ----
__global__ __launch_bounds__(256) void k_prep(const float* __restrict__ h,
                                              unsigned short* __restrict__ hb,
                                              const float* __restrict__ w,
                                              const float* __restrict__ s,
                                              unsigned short* __restrict__ wgb,
                                              const float* __restrict__ wdn,
                                              const float* __restrict__ sdn,
                                              unsigned short* __restrict__ wdb,
                                              const int* __restrict__ ids,
                                              const float* __restrict__ tw,
                                              int* __restrict__ wsI) {
  if (blockIdx.x == PREPB) {
    __shared__ int cnt[8], off[8], cur[8];
    const int tid = threadIdx.x;
    if (tid < 8) { cnt[tid] = 0; cur[tid] = 0; }
    __syncthreads();
    for (int g = tid; g < NENT; g += 256)
      atomicAdd(&cnt[ids[g] & 7], 1);
    __syncthreads();
    if (tid == 0) {
      int sum = 0, n1 = 0, n2 = 0;
      int* wl1 = wsI + 48;
      int* wl2 = wsI + 96;
      for (int e = 0; e < 8; e++) {
        off[e] = sum; wsI[16 + e] = sum; wsI[e] = cnt[e];
        int c = cnt[e]; sum += c;
        int nb1 = (c + 127) >> 7;
        for (int rb = 0; rb < nb1; rb++) wl1[n1++] = (e << 8) | rb;
        int nb2 = (c + 255) >> 8;
        for (int rb = 0; rb < nb2; rb++) wl2[n2++] = (e << 8) | rb;
      }
      wsI[24] = n1; wsI[25] = n2;
    }
    __syncthreads();
    int*   etok = wsI + ETOK_OFF;
    float* ew   = (float*)(wsI + ETOK_OFF + NENT);
    int*   inv  = wsI + ETOK_OFF + 2 * NENT;
    for (int g = threadIdx.x; g < NENT; g += 256) {
      int e = ids[g] & 7;
      int pos = atomicAdd(&cur[e], 1);
      int idx = off[e] + pos;
      etok[idx] = g >> 1;
      ew[idx]   = tw[g];
      inv[g]    = idx;
    }
    return;
  }

  const int gid = blockIdx.x * 256 + threadIdx.x;
  const int NH = T_TOK * HDIM / 8;                  // 524288
  if (gid < NH) {
    const floatx4 v0 = *(const floatx4*)(h + (size_t)gid * 8);
    const floatx4 v1 = *(const floatx4*)(h + (size_t)gid * 8 + 4);
    *(short8v*)(hb + (size_t)gid * 8) = cvt8(v0, v1, 1.f);
  }
  const int NG = NEXP * 2 * FDIM * HDIM / 8;        // 4194304
  for (int c = gid; c < NG; c += PREPB * 256) {
    int h8  = c & 255;
    int row = c >> 8;
    int e   = row >> 11;
    int orow = row & 2047;
    float sc = s[e * 256 + (orow >> 7) * 16 + (h8 >> 4)];
    const floatx4 v0 = *(const floatx4*)(w + (size_t)c * 8);
    const floatx4 v1 = *(const floatx4*)(w + (size_t)c * 8 + 4);
    *(short8v*)(wgb + (size_t)c * 8) = cvt8(v0, v1, sc);
  }
  const int ND = NEXP * HDIM * FDIM / 8;            // 2097152
  for (int c = gid; c < ND; c += PREPB * 256) {
    int f8  = c & 127;
    int row = c >> 7;
    int e   = row >> 11;
    int hh  = row & 2047;
    float sc = sdn[e * 128 + (hh >> 7) * 8 + (f8 >> 4)];
    const floatx4 v0 = *(const floatx4*)(wdn + (size_t)c * 8);
    const floatx4 v1 = *(const floatx4*)(wdn + (size_t)c * 8 + 4);
    *(short8v*)(wdb + (size_t)c * 8) = cvt8(v0, v1, sc);
  }
}

// ---- GEMM1: act = silu(h@Wg^T)*(h@Wu^T); BM=256 x 32 act-cols, BK=64 (r18) ----
__global__ __launch_bounds__(256, 4) void k_gemm1n(
    const unsigned short* __restrict__ hb,
    const unsigned short* __restrict__ wgb,
    const int* __restrict__ wsI,
    unsigned short* __restrict__ act)
{
  if ((int)blockIdx.x >= wsI[25]) return;
  const int item = wsI[96 + blockIdx.x];
  const int e    = item >> 8;
  const int r0   = (item & 255) << 8;
  const int cnt  = wsI[e];
  const int off  = wsI[16 + e];
  const int c0   = blockIdx.y * 32;          // act col base
  const int* etok = wsI + ETOK_OFF;

  __shared__ unsigned short As[256][64];     // 32 KB
  __shared__ unsigned short Bs[64][64];      // 8 KB

  const int tid = threadIdx.x, lane = tid & 63, w = tid >> 6;
  const int kg = lane >> 4, l15 = lane & 15, lr = lane >> 3, lc = lane & 7;

  unsigned int aoff[8];
#pragma unroll
  for (int i = 0; i < 8; i++) {
    int ra  = w * 64 + i * 8 + lr;
    int swz = (lc ^ (ra & 7)) * 8;
    int ent = r0 + ra; if (ent >= cnt) ent = cnt - 1;
    aoff[i] = (unsigned)etok[off + ent] * 2048u + (unsigned)swz;
  }
  unsigned int boff[2];
#pragma unroll
  for (int i = 0; i < 2; i++) {
    int rb  = (w * 2 + i) * 8 + lr;          // [0,64): 32 gate + 32 up
    int swz = (lc ^ (rb & 7)) * 8;
    int gr  = (rb < 32) ? (c0 + rb) : (1024 + c0 + rb - 32);
    boff[i] = ((unsigned)e * 2048u + (unsigned)gr) * 2048u + (unsigned)swz;
  }

  floatx4 acc[4][4] = {};

  for (int k0 = 0; k0 < HDIM; k0 += 64) {
#pragma unroll
    for (int i = 0; i < 8; i++)
      gll16(hb + aoff[i] + k0, (char*)As + (w * 8 + i) * 1024);
#pragma unroll
    for (int i = 0; i < 2; i++)
      gll16(wgb + boff[i] + k0, (char*)Bs + (w * 2 + i) * 1024);
    __syncthreads();

    const char* Ab = (const char*)As;
    const char* Bb = (const char*)Bs;
#pragma unroll
    for (int ks = 0; ks < 2; ks++) {
      short8v a[4], b[4];
#pragma unroll
      for (int m = 0; m < 4; m++) {
        int r = w * 64 + m * 16 + l15;
        a[m] = *(const short8v*)(Ab + r * 128 + (((ks * 4 + kg) ^ (r & 7)) << 4));
      }
#pragma unroll
      for (int n = 0; n < 4; n++) {
        int rb = n * 16 + l15;
        b[n] = *(const short8v*)(Bb + rb * 128 + (((ks * 4 + kg) ^ (rb & 7)) << 4));
      }
#pragma unroll
      for (int m = 0; m < 4; m++)
#pragma unroll
        for (int n = 0; n < 4; n++)
          acc[m][n] = __builtin_amdgcn_mfma_f32_16x16x32_bf16(a[m], b[n], acc[m][n], 0, 0, 0);
    }
    __syncthreads();
  }

#pragma unroll
  for (int m = 0; m < 4; m++) {
    int rbase = r0 + w * 64 + m * 16 + kg * 4;
#pragma unroll
    for (int reg = 0; reg < 4; reg++) {
      int rr = rbase + reg;
      if (rr < cnt) {
#pragma unroll
        for (int n = 0; n < 2; n++) {
          float g = acc[m][n][reg];       // gate col c0 + n*16 + l15
          float u = acc[m][n + 2][reg];   // matching up
          float a = g / (1.f + __expf(-g)) * u;
          act[(size_t)(off + rr) * FDIM + c0 + n * 16 + l15] = f2bf(a);
        }
      }
    }
  }
}

// ---- GEMM2: out[tok] += w_entry*(act @ Wdn^T); BM=256 x 64 h-cols, BK=64 ----
// r18 form, atomic epilogue (oe + k_reduce removed).
__global__ __launch_bounds__(256, 4) void k_gemm2n(
    const unsigned short* __restrict__ wdb,
    const int* __restrict__ wsI,
    const unsigned short* __restrict__ act,
    float* __restrict__ out)
{
  if ((int)blockIdx.x >= wsI[25]) return;
  const int item = wsI[96 + blockIdx.x];
  const int e    = item >> 8;
  const int r0   = (item & 255) << 8;
  const int cnt  = wsI[e];
  const int off  = wsI[16 + e];
  const int c0   = blockIdx.y * 64;          // h col base
  const int* etok = wsI + ETOK_OFF;
  const float* ew = (const float*)(wsI + ETOK_OFF + NENT);

  __shared__ unsigned short As[256][64];     // 32 KB
  __shared__ unsigned short Bs[64][64];      // 8 KB

  const int tid = threadIdx.x, lane = tid & 63, w = tid >> 6;
  const int kg = lane >> 4, l15 = lane & 15, lr = lane >> 3, lc = lane & 7;

  unsigned int aoff[8];
#pragma unroll
  for (int i = 0; i < 8; i++) {
    int ra  = w * 64 + i * 8 + lr;
    int swz = (lc ^ (ra & 7)) * 8;
    int ent = r0 + ra; if (ent >= cnt) ent = cnt - 1;
    aoff[i] = (unsigned)(off + ent) * 1024u + (unsigned)swz;
  }
  unsigned int boff[2];
#pragma unroll
  for (int i = 0; i < 2; i++) {
    int rb  = (w * 2 + i) * 8 + lr;          // [0,64) h-rows
    int swz = (lc ^ (rb & 7)) * 8;
    boff[i] = ((unsigned)e * 2048u + (unsigned)(c0 + rb)) * 1024u + (unsigned)swz;
  }

  floatx4 acc[4][4] = {};

  for (int k0 = 0; k0 < FDIM; k0 += 64) {
#pragma unroll
    for (int i = 0; i < 8; i++)
      gll16(act + aoff[i] + k0, (char*)As + (w * 8 + i) * 1024);
#pragma unroll
    for (int i = 0; i < 2; i++)
      gll16(wdb + boff[i] + k0, (char*)Bs + (w * 2 + i) * 1024);
    __syncthreads();

    const char* Ab = (const char*)As;
    const char* Bb = (const char*)Bs;
#pragma unroll
    for (int ks = 0; ks < 2; ks++) {
      short8v a[4], b[4];
#pragma unroll
      for (int m = 0; m < 4; m++) {
        int r = w * 64 + m * 16 + l15;
        a[m] = *(const short8v*)(Ab + r * 128 + (((ks * 4 + kg) ^ (r & 7)) << 4));
      }
#pragma unroll
      for (int n = 0; n < 4; n++) {
        int rb = n * 16 + l15;
        b[n] = *(const short8v*)(Bb + rb * 128 + (((ks * 4 + kg) ^ (rb & 7)) << 4));
      }
#pragma unroll
      for (int m = 0; m < 4; m++)
#pragma unroll
        for (int n = 0; n < 4; n++)
          acc[m][n] = __builtin_amdgcn_mfma_f32_16x16x32_bf16(a[m], b[n], acc[m][n], 0, 0, 0);
    }
    __syncthreads();
  }

#pragma unroll
  for (int m = 0; m < 4; m++) {
    int rbase = r0 + w * 64 + m * 16 + kg * 4;
#pragma unroll
    for (int reg = 0; reg < 4; reg++) {
      int rr = rbase + reg;
      if (rr < cnt) {
        int tok   = etok[off + rr];
        float wgt = ew[off + rr];
#pragma unroll
        for (int n = 0; n < 4; n++)
          atomicAdd(&out[(size_t)tok * HDIM + c0 + n * 16 + l15],
                    wgt * acc[m][n][reg]);
      }
    }
  }
}

// ================= fallback (round-1 passing kernels) =================
__global__ __launch_bounds__(256) void k_gemm1_fb(
    const float* __restrict__ hidden, const float* __restrict__ wgu,
    const float* __restrict__ sgu, const int* __restrict__ wsI,
    unsigned short* __restrict__ act)
{
  const int e = blockIdx.y; const int cnt = wsI[e];
  const int r0 = blockIdx.x * 128; if (r0 >= cnt) return;
  const int off = wsI[16 + e]; const int c0 = blockIdx.z * 64;
  const int* etok = wsI + ETOK_OFF;
  __shared__ unsigned short As[128][40]; __shared__ unsigned short Bs[128][40];
  const int tid = threadIdx.x, lane = tid & 63, wv = tid >> 6;
  const int wr = (wv >> 1) * 64, wc = wv & 1, kg = lane >> 4, l15 = lane & 15;
  floatx4 acc[4][4] = {};
  for (int k0 = 0; k0 < HDIM; k0 += 32) {
#pragma unroll
    for (int c = tid; c < 1024; c += 256) {
      int row = c >> 3, k4 = c & 7;
      int rg = r0 + row; if (rg >= cnt) rg = cnt - 1;
      int tok = etok[off + rg];
      const floatx4 v = *(const floatx4*)&hidden[(size_t)tok * HDIM + k0 + k4 * 4];
      ushort4v o = { f2bf(v.x), f2bf(v.y), f2bf(v.z), f2bf(v.w) };
      *(ushort4v*)&As[row][k4 * 4] = o;
    }
#pragma unroll
    for (int c = tid; c < 1024; c += 256) {
      int row = c >> 3, k4 = c & 7;
      int gr = (row < 64) ? (c0 + row) : (FDIM + c0 + row - 64);
      float s = sgu[e * 256 + (gr >> 7) * 16 + (k0 >> 7)];
      const floatx4 v = *(const floatx4*)&wgu[((size_t)e * 2048 + gr) * HDIM + k0 + k4 * 4];
      ushort4v o = { f2bf(v.x * s), f2bf(v.y * s), f2bf(v.z * s), f2bf(v.w * s) };
      *(ushort4v*)&Bs[row][k4 * 4] = o;
    }
    __syncthreads();
    short8v a[4], b[4];
#pragma unroll
    for (int m = 0; m < 4; m++) a[m] = *(const short8v*)&As[wr + m * 16 + l15][kg * 8];
#pragma unroll
    for (int n = 0; n < 4; n++) {
      int br = (n < 2) ? (wc * 32 + n * 16) : (64 + wc * 32 + (n - 2) * 16);
      b[n] = *(const short8v*)&Bs[br + l15][kg * 8];
    }
#pragma unroll
    for (int m = 0; m < 4; m++)
#pragma unroll
      for (int n = 0; n < 4; n++)
        acc[m][n] = __builtin_amdgcn_mfma_f32_16x16x32_bf16(a[m], b[n], acc[m][n], 0, 0, 0);
    __syncthreads();
  }
#pragma unroll
  for (int m = 0; m < 4; m++) {
    int rbase = r0 + wr + m * 16 + kg * 4;
#pragma unroll
    for (int reg = 0; reg < 4; reg++) {
      int rr = rbase + reg;
      if (rr < cnt) {
#pragma unroll
        for (int n = 0; n < 2; n++) {
          float g = acc[m][n][reg], u = acc[m][n + 2][reg];
          float a = g / (1.f + expf(-g)) * u;
          act[(size_t)(off + rr) * FDIM + c0 + wc * 32 + n * 16 + l15] = f2bf(a);
        }
      }
    }
  }
}

__global__ __launch_bounds__(256) void k_gemm2_fb(
    const float* __restrict__ wdn, const float* __restrict__ sdn,
    const int* __restrict__ wsI, const unsigned short* __restrict__ act,
    float* __restrict__ out)
{
  const int e = blockIdx.y; const int cnt = wsI[e];
  const int r0 = blockIdx.x * 128; if (r0 >= cnt) return;
  const int off = wsI[16 + e]; const int c0 = blockIdx.z * 128;
  const int* etok = wsI + ETOK_OFF;
  const float* ew = (const float*)(wsI + ETOK_OFF + NENT);
  __shared__ unsigned short As[128][40]; __shared__ unsigned short Bs[128][40];
  const int tid = threadIdx.x, lane = tid & 63, wv = tid >> 6;
  const int wr = (wv >> 1) * 64, wc = wv & 1, kg = lane >> 4, l15 = lane & 15;
  floatx4 acc[4][4] = {};
  for (int k0 = 0; k0 < FDIM; k0 += 32) {
#pragma unroll
    for (int c = tid; c < 512; c += 256) {
      int row = c >> 2, k8 = c & 3;
      int rg = r0 + row; if (rg >= cnt) rg = cnt - 1;
      short8v v = *(const short8v*)&act[(size_t)(off + rg) * FDIM + k0 + k8 * 8];
      *(short8v*)&As[row][k8 * 8] = v;
    }
#pragma unroll
    for (int c = tid; c < 1024; c += 256) {
      int row = c >> 3, k4 = c & 7;
      int gr = c0 + row;
      float s = sdn[e * 128 + (gr >> 7) * 8 + (k0 >> 7)];
      const floatx4 v = *(const floatx4*)&wdn[((size_t)e * HDIM + gr) * FDIM + k0 + k4 * 4];
      ushort4v o = { f2bf(v.x * s), f2bf(v.y * s), f2bf(v.z * s), f2bf(v.w * s) };
      *(ushort4v*)&Bs[row][k4 * 4] = o;
    }
    __syncthreads();
    short8v a[4], b[4];
#pragma unroll
    for (int m = 0; m < 4; m++) a[m] = *(const short8v*)&As[wr + m * 16 + l15][kg * 8];
#pragma unroll
    for (int n = 0; n < 4; n++) b[n] = *(const short8v*)&Bs[wc * 64 + n * 16 + l15][kg * 8];
#pragma unroll
    for (int m = 0; m < 4; m++)
#pragma unroll
      for (int n = 0; n < 4; n++)
        acc[m][n] = __builtin_amdgcn_mfma_f32_16x16x32_bf16(a[m], b[n], acc[m][n], 0, 0, 0);
    __syncthreads();
  }
#pragma unroll
  for (int m = 0; m < 4; m++) {
    int rbase = r0 + wr + m * 16 + kg * 4;
#pragma unroll
    for (int reg = 0; reg < 4; reg++) {
      int rr = rbase + reg;
      if (rr < cnt) {
        int tok = etok[off + rr];
        float ww = ew[off + rr];
#pragma unroll
        for (int n = 0; n < 4; n++)
          atomicAdd(&out[(size_t)tok * HDIM + c0 + wc * 64 + n * 16 + l15], ww * acc[m][n][reg]);
      }
    }
  }
}

extern "C" void kernel_launch(void* const* d_in, const int* in_sizes, int n_in,
                              void* d_out, int out_size, void* d_ws, size_t ws_size,
                              hipStream_t stream) {
  const float* hidden = (const float*)d_in[0];
  const float* tw     = (const float*)d_in[1];
  const int*   ids    = (const int*)d_in[2];
  const float* wgu    = (const float*)d_in[3];
  const float* sgu    = (const float*)d_in[4];
  const float* wdn    = (const float*)d_in[5];
  const float* sdn    = (const float*)d_in[6];
  float* out = (float*)d_out;
  int* wsI = (int*)d_ws;

  const size_t NEED = 65536ull + (112ull << 20);
  if (ws_size >= NEED) {
    unsigned short* hb  = (unsigned short*)((char*)d_ws + 65536);
    unsigned short* wgb = hb  + (size_t)T_TOK * HDIM;
    unsigned short* wdb = wgb + (size_t)NEXP * 2 * FDIM * HDIM;
    unsigned short* act = wdb + (size_t)NEXP * HDIM * FDIM;

    k_zero<<<2048, 256, 0, stream>>>(out);
    k_prep<<<PREPB + 1, 256, 0, stream>>>(hidden, hb, wgu, sgu, wgb,
                                          wdn, sdn, wdb, ids, tw, wsI);

    dim3 g1(WMAX1, 32);
    k_gemm1n<<<g1, 256, 0, stream>>>(hb, wgb, wsI, act);
    dim3 g2(WMAX1, 32);
    k_gemm2n<<<g2, 256, 0, stream>>>(wdb, wsI, act, out);
  } else {
    k_zero <<<2048, 256, 0, stream>>>(out);
    k_route<<<1, 256, 0, stream>>>(ids, tw, wsI);
    unsigned short* act = (unsigned short*)((char*)d_ws + 65536);
    dim3 g1(NENT / 128, NEXP, FDIM / 64);
    k_gemm1_fb<<<g1, 256, 0, stream>>>(hidden, wgu, sgu, wsI, act);
    dim3 g2(NENT / 128, NEXP, HDIM / 128);
    k_gemm2_fb<<<g2, 256, 0, stream>>>(wdn, sdn, wsI, act, out);
  }
}

// Round 21
// 162.380 us; speedup vs baseline: 1.1304x; 1.0910x over previous
//
#include <hip/hip_runtime.h>
#include <hip/hip_bf16.h>

#define T_TOK 2048
#define HDIM  2048
#define FDIM  1024
#define NEXP  8
#define KSEL  2
#define NENT  (T_TOK*KSEL)   // 4096 routing entries
#define WMAX1 24             // max 256-row work items
#define PREPB 8192           // streaming blocks in k_prep (block PREPB = routing)

typedef __attribute__((ext_vector_type(8))) short   short8v;
typedef __attribute__((ext_vector_type(4))) float   floatx4;
typedef __attribute__((ext_vector_type(4))) unsigned short ushort4v;

__device__ __forceinline__ unsigned short f2bf(float f) {
  unsigned int u = __builtin_bit_cast(unsigned int, f);
  u += 0x7FFFu + ((u >> 16) & 1u);
  return (unsigned short)(u >> 16);
}

__device__ __forceinline__ short8v cvt8(floatx4 v0, floatx4 v1, float sc) {
  short8v r = { (short)f2bf(v0.x*sc), (short)f2bf(v0.y*sc),
                (short)f2bf(v0.z*sc), (short)f2bf(v0.w*sc),
                (short)f2bf(v1.x*sc), (short)f2bf(v1.y*sc),
                (short)f2bf(v1.z*sc), (short)f2bf(v1.w*sc) };
  return r;
}

__device__ __forceinline__ void gll16(const void* g, void* l) {
  __builtin_amdgcn_global_load_lds(
      (const __attribute__((address_space(1))) unsigned int*)g,
      (__attribute__((address_space(3))) unsigned int*)l, 16, 0, 0);
}

// ---- workspace layout ----
// wsI[0:8) cnt | wsI[16:24) offsets | wsI[24] nWork128 | wsI[25] nWork256
// wsI[48:88) wl128 | wsI[96:120) wl256
// wsI[128:+4096) entry token | (float*)[4096] entry weight | [4096] inv map
// byte 65536: hb (8Mi) | wgb (64Mi) | wdb (32Mi) | act (8Mi) | oe (32Mi)
#define ETOK_OFF 128

// fallback-path zero (never hipMemsetAsync: rocclr fill kernel is slow)
__global__ __launch_bounds__(256) void k_zero(float* __restrict__ p) {
  const int N = T_TOK * HDIM / 4;
  for (int c = blockIdx.x * 256 + threadIdx.x; c < N; c += 2048 * 256) {
    floatx4 z = {0.f, 0.f, 0.f, 0.f};
    *(floatx4*)(p + (size_t)c * 4) = z;
  }
}

// standalone routing (fallback path)
__global__ void k_route(const int* __restrict__ ids, const float* __restrict__ tw,
                        int* __restrict__ wsI) {
  __shared__ int cnt[8], off[8], cur[8];
  const int tid = threadIdx.x;
  if (tid < 8) { cnt[tid] = 0; cur[tid] = 0; }
  __syncthreads();
  for (int g = tid; g < NENT; g += 256)
    atomicAdd(&cnt[ids[g] & 7], 1);
  __syncthreads();
  if (tid == 0) {
    int s = 0, n1 = 0, n2 = 0;
    int* wl1 = wsI + 48;
    int* wl2 = wsI + 96;
    for (int e = 0; e < 8; e++) {
      off[e] = s; wsI[16 + e] = s; wsI[e] = cnt[e];
      int c = cnt[e]; s += c;
      int nb1 = (c + 127) >> 7;
      for (int rb = 0; rb < nb1; rb++) wl1[n1++] = (e << 8) | rb;
      int nb2 = (c + 255) >> 8;
      for (int rb = 0; rb < nb2; rb++) wl2[n2++] = (e << 8) | rb;
    }
    wsI[24] = n1; wsI[25] = n2;
  }
  __syncthreads();
  int*   etok = wsI + ETOK_OFF;
  float* ew   = (float*)(wsI + ETOK_OFF + NENT);
  int*   inv  = wsI + ETOK_OFF + 2 * NENT;
  for (int g = tid; g < NENT; g += 256) {
    int e = ids[g] & 7;
    int pos = atomicAdd(&cur[e], 1);
    int idx = off[e] + pos;
    etok[idx] = g >> 1;
    ew[idx]   = tw[g];
    inv[g]    = idx;
  }
}

// ---- fused prep: hidden->bf16, BOTH weight dequants, AND routing ----
__global__ __launch_bounds__(256) void k_prep(const float* __restrict__ h,
                                              unsigned short* __restrict__ hb,
                                              const float* __restrict__ w,
                                              const float* __restrict__ s,
                                              unsigned short* __restrict__ wgb,
                                              const float* __restrict__ wdn,
                                              const float* __restrict__ sdn,
                                              unsigned short* __restrict__ wdb,
                                              const int* __restrict__ ids,
                                              const float* __restrict__ tw,
                                              int* __restrict__ wsI) {
  if (blockIdx.x == PREPB) {
    __shared__ int cnt[8], off[8], cur[8];
    const int tid = threadIdx.x;
    if (tid < 8) { cnt[tid] = 0; cur[tid] = 0; }
    __syncthreads();
    for (int g = tid; g < NENT; g += 256)
      atomicAdd(&cnt[ids[g] & 7], 1);
    __syncthreads();
    if (tid == 0) {
      int sum = 0, n1 = 0, n2 = 0;
      int* wl1 = wsI + 48;
      int* wl2 = wsI + 96;
      for (int e = 0; e < 8; e++) {
        off[e] = sum; wsI[16 + e] = sum; wsI[e] = cnt[e];
        int c = cnt[e]; sum += c;
        int nb1 = (c + 127) >> 7;
        for (int rb = 0; rb < nb1; rb++) wl1[n1++] = (e << 8) | rb;
        int nb2 = (c + 255) >> 8;
        for (int rb = 0; rb < nb2; rb++) wl2[n2++] = (e << 8) | rb;
      }
      wsI[24] = n1; wsI[25] = n2;
    }
    __syncthreads();
    int*   etok = wsI + ETOK_OFF;
    float* ew   = (float*)(wsI + ETOK_OFF + NENT);
    int*   inv  = wsI + ETOK_OFF + 2 * NENT;
    for (int g = threadIdx.x; g < NENT; g += 256) {
      int e = ids[g] & 7;
      int pos = atomicAdd(&cur[e], 1);
      int idx = off[e] + pos;
      etok[idx] = g >> 1;
      ew[idx]   = tw[g];
      inv[g]    = idx;
    }
    return;
  }

  const int gid = blockIdx.x * 256 + threadIdx.x;
  const int NH = T_TOK * HDIM / 8;                  // 524288
  if (gid < NH) {
    const floatx4 v0 = *(const floatx4*)(h + (size_t)gid * 8);
    const floatx4 v1 = *(const floatx4*)(h + (size_t)gid * 8 + 4);
    *(short8v*)(hb + (size_t)gid * 8) = cvt8(v0, v1, 1.f);
  }
  const int NG = NEXP * 2 * FDIM * HDIM / 8;        // 4194304
  for (int c = gid; c < NG; c += PREPB * 256) {
    int h8  = c & 255;
    int row = c >> 8;
    int e   = row >> 11;
    int orow = row & 2047;
    float sc = s[e * 256 + (orow >> 7) * 16 + (h8 >> 4)];
    const floatx4 v0 = *(const floatx4*)(w + (size_t)c * 8);
    const floatx4 v1 = *(const floatx4*)(w + (size_t)c * 8 + 4);
    *(short8v*)(wgb + (size_t)c * 8) = cvt8(v0, v1, sc);
  }
  const int ND = NEXP * HDIM * FDIM / 8;            // 2097152
  for (int c = gid; c < ND; c += PREPB * 256) {
    int f8  = c & 127;
    int row = c >> 7;
    int e   = row >> 11;
    int hh  = row & 2047;
    float sc = sdn[e * 128 + (hh >> 7) * 8 + (f8 >> 4)];
    const floatx4 v0 = *(const floatx4*)(wdn + (size_t)c * 8);
    const floatx4 v1 = *(const floatx4*)(wdn + (size_t)c * 8 + 4);
    *(short8v*)(wdb + (size_t)c * 8) = cvt8(v0, v1, sc);
  }
}

// ---- GEMM1: act = silu(h@Wg^T)*(h@Wu^T); BM=256 x 32 act-cols, BK=64 ----
// grid (WMAX1, 32): wave w owns rows [w*64,w*64+64), all 32 cols.
__global__ __launch_bounds__(256, 4) void k_gemm1n(
    const unsigned short* __restrict__ hb,
    const unsigned short* __restrict__ wgb,
    const int* __restrict__ wsI,
    unsigned short* __restrict__ act)
{
  if ((int)blockIdx.x >= wsI[25]) return;
  const int item = wsI[96 + blockIdx.x];
  const int e    = item >> 8;
  const int r0   = (item & 255) << 8;
  const int cnt  = wsI[e];
  const int off  = wsI[16 + e];
  const int c0   = blockIdx.y * 32;          // act col base
  const int* etok = wsI + ETOK_OFF;

  __shared__ unsigned short As[256][64];     // 32 KB
  __shared__ unsigned short Bs[64][64];      // 8 KB

  const int tid = threadIdx.x, lane = tid & 63, w = tid >> 6;
  const int kg = lane >> 4, l15 = lane & 15, lr = lane >> 3, lc = lane & 7;

  unsigned int aoff[8];
#pragma unroll
  for (int i = 0; i < 8; i++) {
    int ra  = w * 64 + i * 8 + lr;
    int swz = (lc ^ (ra & 7)) * 8;
    int ent = r0 + ra; if (ent >= cnt) ent = cnt - 1;
    aoff[i] = (unsigned)etok[off + ent] * 2048u + (unsigned)swz;
  }
  unsigned int boff[2];
#pragma unroll
  for (int i = 0; i < 2; i++) {
    int rb  = (w * 2 + i) * 8 + lr;          // [0,64): 32 gate + 32 up
    int swz = (lc ^ (rb & 7)) * 8;
    int gr  = (rb < 32) ? (c0 + rb) : (1024 + c0 + rb - 32);
    boff[i] = ((unsigned)e * 2048u + (unsigned)gr) * 2048u + (unsigned)swz;
  }

  floatx4 acc[4][4] = {};

  for (int k0 = 0; k0 < HDIM; k0 += 64) {
#pragma unroll
    for (int i = 0; i < 8; i++)
      gll16(hb + aoff[i] + k0, (char*)As + (w * 8 + i) * 1024);
#pragma unroll
    for (int i = 0; i < 2; i++)
      gll16(wgb + boff[i] + k0, (char*)Bs + (w * 2 + i) * 1024);
    __syncthreads();

    const char* Ab = (const char*)As;
    const char* Bb = (const char*)Bs;
#pragma unroll
    for (int ks = 0; ks < 2; ks++) {
      short8v a[4], b[4];
#pragma unroll
      for (int m = 0; m < 4; m++) {
        int r = w * 64 + m * 16 + l15;
        a[m] = *(const short8v*)(Ab + r * 128 + (((ks * 4 + kg) ^ (r & 7)) << 4));
      }
#pragma unroll
      for (int n = 0; n < 4; n++) {
        int rb = n * 16 + l15;
        b[n] = *(const short8v*)(Bb + rb * 128 + (((ks * 4 + kg) ^ (rb & 7)) << 4));
      }
#pragma unroll
      for (int m = 0; m < 4; m++)
#pragma unroll
        for (int n = 0; n < 4; n++)
          acc[m][n] = __builtin_amdgcn_mfma_f32_16x16x32_bf16(a[m], b[n], acc[m][n], 0, 0, 0);
    }
    __syncthreads();
  }

#pragma unroll
  for (int m = 0; m < 4; m++) {
    int rbase = r0 + w * 64 + m * 16 + kg * 4;
#pragma unroll
    for (int reg = 0; reg < 4; reg++) {
      int rr = rbase + reg;
      if (rr < cnt) {
#pragma unroll
        for (int n = 0; n < 2; n++) {
          float g = acc[m][n][reg];       // gate col c0 + n*16 + l15
          float u = acc[m][n + 2][reg];   // matching up
          float a = g / (1.f + __expf(-g)) * u;
          act[(size_t)(off + rr) * FDIM + c0 + n * 16 + l15] = f2bf(a);
        }
      }
    }
  }
}

// ---- GEMM2: oe[entry] = w_entry * (act @ Wdn^T); BM=256 x 64 h-cols ----
__global__ __launch_bounds__(256, 4) void k_gemm2n(
    const unsigned short* __restrict__ wdb,
    const int* __restrict__ wsI,
    const unsigned short* __restrict__ act,
    float* __restrict__ oe)
{
  if ((int)blockIdx.x >= wsI[25]) return;
  const int item = wsI[96 + blockIdx.x];
  const int e    = item >> 8;
  const int r0   = (item & 255) << 8;
  const int cnt  = wsI[e];
  const int off  = wsI[16 + e];
  const int c0   = blockIdx.y * 64;          // h col base
  const float* ew = (const float*)(wsI + ETOK_OFF + NENT);

  __shared__ unsigned short As[256][64];     // 32 KB
  __shared__ unsigned short Bs[64][64];      // 8 KB

  const int tid = threadIdx.x, lane = tid & 63, w = tid >> 6;
  const int kg = lane >> 4, l15 = lane & 15, lr = lane >> 3, lc = lane & 7;

  unsigned int aoff[8];
#pragma unroll
  for (int i = 0; i < 8; i++) {
    int ra  = w * 64 + i * 8 + lr;
    int swz = (lc ^ (ra & 7)) * 8;
    int ent = r0 + ra; if (ent >= cnt) ent = cnt - 1;
    aoff[i] = (unsigned)(off + ent) * 1024u + (unsigned)swz;
  }
  unsigned int boff[2];
#pragma unroll
  for (int i = 0; i < 2; i++) {
    int rb  = (w * 2 + i) * 8 + lr;          // [0,64) h-rows
    int swz = (lc ^ (rb & 7)) * 8;
    boff[i] = ((unsigned)e * 2048u + (unsigned)(c0 + rb)) * 1024u + (unsigned)swz;
  }

  floatx4 acc[4][4] = {};

  for (int k0 = 0; k0 < FDIM; k0 += 64) {
#pragma unroll
    for (int i = 0; i < 8; i++)
      gll16(act + aoff[i] + k0, (char*)As + (w * 8 + i) * 1024);
#pragma unroll
    for (int i = 0; i < 2; i++)
      gll16(wdb + boff[i] + k0, (char*)Bs + (w * 2 + i) * 1024);
    __syncthreads();

    const char* Ab = (const char*)As;
    const char* Bb = (const char*)Bs;
#pragma unroll
    for (int ks = 0; ks < 2; ks++) {
      short8v a[4], b[4];
#pragma unroll
      for (int m = 0; m < 4; m++) {
        int r = w * 64 + m * 16 + l15;
        a[m] = *(const short8v*)(Ab + r * 128 + (((ks * 4 + kg) ^ (r & 7)) << 4));
      }
#pragma unroll
      for (int n = 0; n < 4; n++) {
        int rb = n * 16 + l15;
        b[n] = *(const short8v*)(Bb + rb * 128 + (((ks * 4 + kg) ^ (rb & 7)) << 4));
      }
#pragma unroll
      for (int m = 0; m < 4; m++)
#pragma unroll
        for (int n = 0; n < 4; n++)
          acc[m][n] = __builtin_amdgcn_mfma_f32_16x16x32_bf16(a[m], b[n], acc[m][n], 0, 0, 0);
    }
    __syncthreads();
  }

#pragma unroll
  for (int m = 0; m < 4; m++) {
    int rbase = r0 + w * 64 + m * 16 + kg * 4;
#pragma unroll
    for (int reg = 0; reg < 4; reg++) {
      int rr = rbase + reg;
      if (rr < cnt) {
        float wgt = ew[off + rr];
#pragma unroll
        for (int n = 0; n < 4; n++)
          oe[(size_t)(off + rr) * HDIM + c0 + n * 16 + l15] = wgt * acc[m][n][reg];
      }
    }
  }
}

__global__ __launch_bounds__(256) void k_reduce(const int* __restrict__ wsI,
                                                const float* __restrict__ oe,
                                                float* __restrict__ out) {
  int i4 = blockIdx.x * 256 + threadIdx.x;
  if (i4 >= T_TOK * HDIM / 4) return;
  int t  = i4 >> 9;
  int h4 = (i4 & 511) * 4;
  const int* inv = wsI + ETOK_OFF + 2 * NENT;
  int e0 = inv[2 * t], e1 = inv[2 * t + 1];
  floatx4 a = *(const floatx4*)&oe[(size_t)e0 * HDIM + h4];
  floatx4 b = *(const floatx4*)&oe[(size_t)e1 * HDIM + h4];
  floatx4 r = a + b;
  *(floatx4*)&out[(size_t)t * HDIM + h4] = r;
}

// ================= fallback (round-1 passing kernels) =================
__global__ __launch_bounds__(256) void k_gemm1_fb(
    const float* __restrict__ hidden, const float* __restrict__ wgu,
    const float* __restrict__ sgu, const int* __restrict__ wsI,
    unsigned short* __restrict__ act)
{
  const int e = blockIdx.y; const int cnt = wsI[e];
  const int r0 = blockIdx.x * 128; if (r0 >= cnt) return;
  const int off = wsI[16 + e]; const int c0 = blockIdx.z * 64;
  const int* etok = wsI + ETOK_OFF;
  __shared__ unsigned short As[128][40]; __shared__ unsigned short Bs[128][40];
  const int tid = threadIdx.x, lane = tid & 63, wv = tid >> 6;
  const int wr = (wv >> 1) * 64, wc = wv & 1, kg = lane >> 4, l15 = lane & 15;
  floatx4 acc[4][4] = {};
  for (int k0 = 0; k0 < HDIM; k0 += 32) {
#pragma unroll
    for (int c = tid; c < 1024; c += 256) {
      int row = c >> 3, k4 = c & 7;
      int rg = r0 + row; if (rg >= cnt) rg = cnt - 1;
      int tok = etok[off + rg];
      const floatx4 v = *(const floatx4*)&hidden[(size_t)tok * HDIM + k0 + k4 * 4];
      ushort4v o = { f2bf(v.x), f2bf(v.y), f2bf(v.z), f2bf(v.w) };
      *(ushort4v*)&As[row][k4 * 4] = o;
    }
#pragma unroll
    for (int c = tid; c < 1024; c += 256) {
      int row = c >> 3, k4 = c & 7;
      int gr = (row < 64) ? (c0 + row) : (FDIM + c0 + row - 64);
      float s = sgu[e * 256 + (gr >> 7) * 16 + (k0 >> 7)];
      const floatx4 v = *(const floatx4*)&wgu[((size_t)e * 2048 + gr) * HDIM + k0 + k4 * 4];
      ushort4v o = { f2bf(v.x * s), f2bf(v.y * s), f2bf(v.z * s), f2bf(v.w * s) };
      *(ushort4v*)&Bs[row][k4 * 4] = o;
    }
    __syncthreads();
    short8v a[4], b[4];
#pragma unroll
    for (int m = 0; m < 4; m++) a[m] = *(const short8v*)&As[wr + m * 16 + l15][kg * 8];
#pragma unroll
    for (int n = 0; n < 4; n++) {
      int br = (n < 2) ? (wc * 32 + n * 16) : (64 + wc * 32 + (n - 2) * 16);
      b[n] = *(const short8v*)&Bs[br + l15][kg * 8];
    }
#pragma unroll
    for (int m = 0; m < 4; m++)
#pragma unroll
      for (int n = 0; n < 4; n++)
        acc[m][n] = __builtin_amdgcn_mfma_f32_16x16x32_bf16(a[m], b[n], acc[m][n], 0, 0, 0);
    __syncthreads();
  }
#pragma unroll
  for (int m = 0; m < 4; m++) {
    int rbase = r0 + wr + m * 16 + kg * 4;
#pragma unroll
    for (int reg = 0; reg < 4; reg++) {
      int rr = rbase + reg;
      if (rr < cnt) {
#pragma unroll
        for (int n = 0; n < 2; n++) {
          float g = acc[m][n][reg], u = acc[m][n + 2][reg];
          float a = g / (1.f + expf(-g)) * u;
          act[(size_t)(off + rr) * FDIM + c0 + wc * 32 + n * 16 + l15] = f2bf(a);
        }
      }
    }
  }
}

__global__ __launch_bounds__(256) void k_gemm2_fb(
    const float* __restrict__ wdn, const float* __restrict__ sdn,
    const int* __restrict__ wsI, const unsigned short* __restrict__ act,
    float* __restrict__ out)
{
  const int e = blockIdx.y; const int cnt = wsI[e];
  const int r0 = blockIdx.x * 128; if (r0 >= cnt) return;
  const int off = wsI[16 + e]; const int c0 = blockIdx.z * 128;
  const int* etok = wsI + ETOK_OFF;
  const float* ew = (const float*)(wsI + ETOK_OFF + NENT);
  __shared__ unsigned short As[128][40]; __shared__ unsigned short Bs[128][40];
  const int tid = threadIdx.x, lane = tid & 63, wv = tid >> 6;
  const int wr = (wv >> 1) * 64, wc = wv & 1, kg = lane >> 4, l15 = lane & 15;
  floatx4 acc[4][4] = {};
  for (int k0 = 0; k0 < FDIM; k0 += 32) {
#pragma unroll
    for (int c = tid; c < 512; c += 256) {
      int row = c >> 2, k8 = c & 3;
      int rg = r0 + row; if (rg >= cnt) rg = cnt - 1;
      short8v v = *(const short8v*)&act[(size_t)(off + rg) * FDIM + k0 + k8 * 8];
      *(short8v*)&As[row][k8 * 8] = v;
    }
#pragma unroll
    for (int c = tid; c < 1024; c += 256) {
      int row = c >> 3, k4 = c & 7;
      int gr = c0 + row;
      float s = sdn[e * 128 + (gr >> 7) * 8 + (k0 >> 7)];
      const floatx4 v = *(const floatx4*)&wdn[((size_t)e * HDIM + gr) * FDIM + k0 + k4 * 4];
      ushort4v o = { f2bf(v.x * s), f2bf(v.y * s), f2bf(v.z * s), f2bf(v.w * s) };
      *(ushort4v*)&Bs[row][k4 * 4] = o;
    }
    __syncthreads();
    short8v a[4], b[4];
#pragma unroll
    for (int m = 0; m < 4; m++) a[m] = *(const short8v*)&As[wr + m * 16 + l15][kg * 8];
#pragma unroll
    for (int n = 0; n < 4; n++) b[n] = *(const short8v*)&Bs[wc * 64 + n * 16 + l15][kg * 8];
#pragma unroll
    for (int m = 0; m < 4; m++)
#pragma unroll
      for (int n = 0; n < 4; n++)
        acc[m][n] = __builtin_amdgcn_mfma_f32_16x16x32_bf16(a[m], b[n], acc[m][n], 0, 0, 0);
    __syncthreads();
  }
#pragma unroll
  for (int m = 0; m < 4; m++) {
    int rbase = r0 + wr + m * 16 + kg * 4;
#pragma unroll
    for (int reg = 0; reg < 4; reg++) {
      int rr = rbase + reg;
      if (rr < cnt) {
        int tok = etok[off + rr];
        float ww = ew[off + rr];
#pragma unroll
        for (int n = 0; n < 4; n++)
          atomicAdd(&out[(size_t)tok * HDIM + c0 + wc * 64 + n * 16 + l15], ww * acc[m][n][reg]);
      }
    }
  }
}

extern "C" void kernel_launch(void* const* d_in, const int* in_sizes, int n_in,
                              void* d_out, int out_size, void* d_ws, size_t ws_size,
                              hipStream_t stream) {
  const float* hidden = (const float*)d_in[0];
  const float* tw     = (const float*)d_in[1];
  const int*   ids    = (const int*)d_in[2];
  const float* wgu    = (const float*)d_in[3];
  const float* sgu    = (const float*)d_in[4];
  const float* wdn    = (const float*)d_in[5];
  const float* sdn    = (const float*)d_in[6];
  float* out = (float*)d_out;
  int* wsI = (int*)d_ws;

  const size_t NEED = 65536ull + (144ull << 20);
  if (ws_size >= NEED) {
    unsigned short* hb  = (unsigned short*)((char*)d_ws + 65536);
    unsigned short* wgb = hb  + (size_t)T_TOK * HDIM;
    unsigned short* wdb = wgb + (size_t)NEXP * 2 * FDIM * HDIM;
    unsigned short* act = wdb + (size_t)NEXP * HDIM * FDIM;
    float*          oe  = (float*)(act + (size_t)NENT * FDIM);

    k_prep<<<PREPB + 1, 256, 0, stream>>>(hidden, hb, wgu, sgu, wgb,
                                          wdn, sdn, wdb, ids, tw, wsI);

    dim3 g1(WMAX1, 32);
    k_gemm1n<<<g1, 256, 0, stream>>>(hb, wgb, wsI, act);
    dim3 g2(WMAX1, 32);
    k_gemm2n<<<g2, 256, 0, stream>>>(wdb, wsI, act, oe);
    k_reduce<<<T_TOK * HDIM / 4 / 256, 256, 0, stream>>>(wsI, oe, out);
  } else {
    k_zero <<<2048, 256, 0, stream>>>(out);
    k_route<<<1, 256, 0, stream>>>(ids, tw, wsI);
    unsigned short* act = (unsigned short*)((char*)d_ws + 65536);
    dim3 g1(NENT / 128, NEXP, FDIM / 64);
    k_gemm1_fb<<<g1, 256, 0, stream>>>(hidden, wgu, sgu, wsI, act);
    dim3 g2(NENT / 128, NEXP, HDIM / 128);
    k_gemm2_fb<<<g2, 256, 0, stream>>>(wdn, sdn, wsI, act, out);
  }
}